// Round 1
// baseline (287.846 us; speedup 1.0000x reference)
//
#include <hip/hip_runtime.h>

#define S_ 2048
#define D_ 512
#define HD_ 64
#define HH_ 8
#define M_ 8192

typedef __attribute__((ext_vector_type(8))) short short8;
typedef __attribute__((ext_vector_type(4))) short short4v;
typedef __attribute__((ext_vector_type(4))) float f32x4;

__device__ __forceinline__ unsigned short f2bf(float f) {
  unsigned u = __builtin_bit_cast(unsigned, f);
  u += 0x7fffu + ((u >> 16) & 1u);
  return (unsigned short)(u >> 16);
}

__device__ __forceinline__ f32x4 mfma16(short8 a, short8 b, f32x4 c) {
  return __builtin_amdgcn_mfma_f32_16x16x32_bf16(a, b, c, 0, 0, 0);
}

#define GLOAD_LDS16(gp, lp)                                                        \
  __builtin_amdgcn_global_load_lds(                                                \
      (const __attribute__((address_space(1))) void*)(gp),                         \
      (__attribute__((address_space(3))) void*)(lp), 16, 0, 0)

// ---------------- converts ----------------

__global__ __launch_bounds__(256) void k_cvt_bf16x8(const float* __restrict__ x,
                                                    short* __restrict__ o) {
  int idx = blockIdx.x * 256 + threadIdx.x;
  const float4* p = (const float4*)x;
  float4 a = p[idx * 2];
  float4 b = p[idx * 2 + 1];
  short8 v;
  v[0] = (short)f2bf(a.x); v[1] = (short)f2bf(a.y);
  v[2] = (short)f2bf(a.z); v[3] = (short)f2bf(a.w);
  v[4] = (short)f2bf(b.x); v[5] = (short)f2bf(b.y);
  v[6] = (short)f2bf(b.z); v[7] = (short)f2bf(b.w);
  *(short8*)&o[idx * 8] = v;
}

// wt[n][k] = bf16(w[k][n]); R (=512) rows in w, C cols. Coalesced writes.
__global__ __launch_bounds__(256) void k_cvt_transpose(const float* __restrict__ w,
                                                       short* __restrict__ wt,
                                                       int C) {
  int idx = blockIdx.x * 256 + threadIdx.x;
  int k = idx & 511;
  int n = idx >> 9;
  if (n < C) wt[n * 512 + k] = (short)f2bf(w[k * C + n]);
}

// ---------------- GEMM (128x128 tile, BK=32, 4 waves) ----------------
// MODE 0: qkv epilogue (scatter to Q/K/VT + bias). MODE 1: fp32 out + bias.
template <int MODE>
__global__ __launch_bounds__(256) void k_gemm(const short* __restrict__ A,
                                              const short* __restrict__ Bt,
                                              const float* __restrict__ bias,
                                              short* __restrict__ Qo,
                                              short* __restrict__ Ko,
                                              short* __restrict__ VTo,
                                              float* __restrict__ Fo) {
  __shared__ short As[4096];  // [128][32]
  __shared__ short Bs[4096];  // [128][32] (rows of B^T)
  const int tid = threadIdx.x;
  const int w = tid >> 6, l = tid & 63, g = l >> 4, c = l & 15;
  const int bm = blockIdx.x * 128, bn = blockIdx.y * 128;
  const int wm = (w >> 1) * 64, wn = (w & 1) * 64;
  const int ch = w * 64 + l;       // chunk 0..255
  const int ar = ch >> 2;          // row 0..63
  const int ac = (ch & 3) * 8;     // elem col
  f32x4 acc[4][4] = {};
  const short* Ap = A + (bm + ar) * 512 + ac;
  const short* Ap2 = Ap + 64 * 512;
  const short* Bp = Bt + (bn + ar) * 512 + ac;
  const short* Bp2 = Bp + 64 * 512;
  short* AsW = &As[w * 512];
  short* BsW = &Bs[w * 512];

  for (int k0 = 0; k0 < 512; k0 += 32) {
    __syncthreads();
    GLOAD_LDS16(Ap + k0, AsW);
    GLOAD_LDS16(Ap2 + k0, AsW + 2048);
    GLOAD_LDS16(Bp + k0, BsW);
    GLOAD_LDS16(Bp2 + k0, BsW + 2048);
    __syncthreads();
    short8 af[4], bfr[4];
#pragma unroll
    for (int mt = 0; mt < 4; mt++)
      af[mt] = *(const short8*)&As[(wm + mt * 16 + c) * 32 + 8 * g];
#pragma unroll
    for (int nt = 0; nt < 4; nt++)
      bfr[nt] = *(const short8*)&Bs[(wn + nt * 16 + c) * 32 + 8 * g];
#pragma unroll
    for (int mt = 0; mt < 4; mt++)
#pragma unroll
      for (int nt = 0; nt < 4; nt++)
        acc[mt][nt] = mfma16(af[mt], bfr[nt], acc[mt][nt]);
  }

  if (MODE == 0) {
#pragma unroll
    for (int nt = 0; nt < 4; nt++) {
      int n = bn + wn + nt * 16 + c;
      float bv = bias[n];
      int h = n / 192;
      int t = n - h * 192;
      int type = t >> 6;   // 0=q 1=k 2=v (uniform across the 16-wide tile)
      int hd = t & 63;
#pragma unroll
      for (int mt = 0; mt < 4; mt++) {
        int m0 = bm + wm + mt * 16 + 4 * g;
        int b = m0 >> 11, s0 = m0 & 2047;
        int bh = b * 8 + h;
        if (type == 2) {
          short4v pk;
#pragma unroll
          for (int r = 0; r < 4; r++) pk[r] = (short)f2bf(acc[mt][nt][r] + bv);
          *(short4v*)&VTo[(bh * 64 + hd) * 2048 + s0] = pk;
        } else {
          short* dst = (type == 0) ? Qo : Ko;
#pragma unroll
          for (int r = 0; r < 4; r++)
            dst[(bh * 2048 + s0 + r) * 64 + hd] = (short)f2bf(acc[mt][nt][r] + bv);
        }
      }
    }
  } else {
#pragma unroll
    for (int nt = 0; nt < 4; nt++) {
      int n = bn + wn + nt * 16 + c;
      float bv = bias[n];
#pragma unroll
      for (int mt = 0; mt < 4; mt++) {
        int m0 = bm + wm + mt * 16 + 4 * g;
#pragma unroll
        for (int r = 0; r < 4; r++) Fo[(m0 + r) * 512 + n] = acc[mt][nt][r] + bv;
      }
    }
  }
}

// ---------------- flash attention ----------------
// grid (S/64, B*H); 4 waves x 16 q-rows. Causal.
__global__ __launch_bounds__(256) void k_attn(const short* __restrict__ Q,
                                              const short* __restrict__ K,
                                              const short* __restrict__ VT,
                                              short* __restrict__ ctx) {
  __shared__ short P[4][16][72];  // per-wave P tile, padded (144B row = bank-uniform)
  const int tid = threadIdx.x;
  const int w = tid >> 6, l = tid & 63, g = l >> 4, c = l & 15;
  const int qt0 = blockIdx.x * 64;
  const int bh = blockIdx.y;
  const int qbase = qt0 + w * 16;
  const short* Qb = Q + bh * S_ * HD_;
  const short* Kb = K + bh * S_ * HD_;
  const short* Vb = VT + bh * HD_ * S_;

  short8 qf0 = *(const short8*)&Qb[(qbase + c) * 64 + 8 * g];
  short8 qf1 = *(const short8*)&Qb[(qbase + c) * 64 + 8 * g + 32];

  float mi[4], li[4];
  f32x4 o[4];
#pragma unroll
  for (int r = 0; r < 4; r++) { mi[r] = -1e30f; li[r] = 0.f; }
#pragma unroll
  for (int nt = 0; nt < 4; nt++) o[nt] = f32x4{0.f, 0.f, 0.f, 0.f};

  const float SC = 0.125f * 1.4426950408889634f;  // scale * log2(e)
  const int kv_end = qt0 + 64;
  const int qrow0 = qbase + 4 * g;

  for (int kv0 = 0; kv0 < kv_end; kv0 += 64) {
    f32x4 sa[4];
#pragma unroll
    for (int nt = 0; nt < 4; nt++) sa[nt] = f32x4{0.f, 0.f, 0.f, 0.f};
#pragma unroll
    for (int nt = 0; nt < 4; nt++) {
      const short* kp = &Kb[(kv0 + nt * 16 + c) * 64 + 8 * g];
      short8 kf0 = *(const short8*)kp;
      short8 kf1 = *(const short8*)(kp + 32);
      sa[nt] = mfma16(qf0, kf0, sa[nt]);
      sa[nt] = mfma16(qf1, kf1, sa[nt]);
    }
    // scale (exp2 domain) + causal mask
    float sv[4][4];
#pragma unroll
    for (int nt = 0; nt < 4; nt++) {
      int kv = kv0 + nt * 16 + c;
#pragma unroll
      for (int r = 0; r < 4; r++)
        sv[nt][r] = (kv <= qrow0 + r) ? sa[nt][r] * SC : -1e30f;
    }
    float rmax[4];
#pragma unroll
    for (int r = 0; r < 4; r++)
      rmax[r] = fmaxf(fmaxf(sv[0][r], sv[1][r]), fmaxf(sv[2][r], sv[3][r]));
#pragma unroll
    for (int off = 1; off < 16; off <<= 1)
#pragma unroll
      for (int r = 0; r < 4; r++)
        rmax[r] = fmaxf(rmax[r], __shfl_xor(rmax[r], off, 64));

    float mn[4], alpha[4], psum[4];
    unsigned short pb[4][4];
#pragma unroll
    for (int r = 0; r < 4; r++) {
      mn[r] = fmaxf(mi[r], rmax[r]);
      alpha[r] = exp2f(mi[r] - mn[r]);
      mi[r] = mn[r];
      psum[r] = 0.f;
    }
#pragma unroll
    for (int nt = 0; nt < 4; nt++)
#pragma unroll
      for (int r = 0; r < 4; r++) {
        float p = exp2f(sv[nt][r] - mn[r]);
        psum[r] += p;
        pb[nt][r] = f2bf(p);
      }
#pragma unroll
    for (int off = 1; off < 16; off <<= 1)
#pragma unroll
      for (int r = 0; r < 4; r++) psum[r] += __shfl_xor(psum[r], off, 64);
#pragma unroll
    for (int r = 0; r < 4; r++) li[r] = li[r] * alpha[r] + psum[r];
#pragma unroll
    for (int nt = 0; nt < 4; nt++)
#pragma unroll
      for (int r = 0; r < 4; r++) o[nt][r] *= alpha[r];

    // P -> LDS (C-layout rows) then read back as A-fragments
#pragma unroll
    for (int nt = 0; nt < 4; nt++)
#pragma unroll
      for (int r = 0; r < 4; r++) P[w][4 * g + r][nt * 16 + c] = (short)pb[nt][r];

#pragma unroll
    for (int kvb = 0; kvb < 2; kvb++) {
      short8 pa = *(const short8*)&P[w][c][kvb * 32 + 8 * g];
#pragma unroll
      for (int nt = 0; nt < 4; nt++) {
        short8 vb = *(const short8*)&Vb[(nt * 16 + c) * S_ + kv0 + kvb * 32 + 8 * g];
        o[nt] = mfma16(pa, vb, o[nt]);
      }
    }
  }

  const int b = bh >> 3, h = bh & 7;
  float inv[4];
#pragma unroll
  for (int r = 0; r < 4; r++) inv[r] = 1.0f / li[r];
#pragma unroll
  for (int nt = 0; nt < 4; nt++)
#pragma unroll
    for (int r = 0; r < 4; r++) {
      int srow = qbase + 4 * g + r;
      ctx[(b * S_ + srow) * 512 + h * 64 + nt * 16 + c] = (short)f2bf(o[nt][r] * inv[r]);
    }
}

// ---------------- launcher ----------------

extern "C" void kernel_launch(void* const* d_in, const int* in_sizes, int n_in,
                              void* d_out, int out_size, void* d_ws, size_t ws_size,
                              hipStream_t stream) {
  const float* x = (const float*)d_in[0];
  // d_in[1] = mask (known causal; unused)
  const float* Wqkv = (const float*)d_in[2];
  const float* bqkv = (const float*)d_in[3];
  const float* Wo = (const float*)d_in[4];
  const float* bo = (const float*)d_in[5];
  float* out = (float*)d_out;

  char* ws = (char*)d_ws;
  short* xb    = (short*)(ws + 0);           // 8 MiB  [8192][512]
  short* wqkvt = (short*)(ws + 8388608);     // 1.5 MiB [1536][512]
  short* wot   = (short*)(ws + 9961472);     // 0.5 MiB [512][512]
  short* Qw    = (short*)(ws + 10485760);    // 8 MiB [32][2048][64]
  short* Kw    = (short*)(ws + 18874368);    // 8 MiB [32][2048][64]
  short* VTw   = (short*)(ws + 27262976);    // 8 MiB [32][64][2048]
  short* ctx   = (short*)(ws + 35651584);    // 8 MiB [8192][512]

  k_cvt_bf16x8<<<2048, 256, 0, stream>>>(x, xb);
  k_cvt_transpose<<<3072, 256, 0, stream>>>(Wqkv, wqkvt, 1536);
  k_cvt_transpose<<<1024, 256, 0, stream>>>(Wo, wot, 512);

  dim3 g1(64, 12);
  k_gemm<0><<<g1, 256, 0, stream>>>(xb, wqkvt, bqkv, Qw, Kw, VTw, nullptr);

  dim3 g2(32, 32);
  k_attn<<<g2, 256, 0, stream>>>(Qw, Kw, VTw, ctx);

  dim3 g3(64, 4);
  k_gemm<1><<<g3, 256, 0, stream>>>(ctx, wot, bo, nullptr, nullptr, nullptr, out);
}

// Round 2
// 144.018 us; speedup vs baseline: 1.9987x; 1.9987x over previous
//
#include <hip/hip_runtime.h>

#define S_ 2048
#define D_ 512
#define HD_ 64
#define HH_ 8
#define M_ 8192

typedef __attribute__((ext_vector_type(8))) short short8;
typedef __attribute__((ext_vector_type(4))) short short4v;
typedef __attribute__((ext_vector_type(4))) float f32x4;

__device__ __forceinline__ unsigned short f2bf(float f) {
  unsigned u = __builtin_bit_cast(unsigned, f);
  u += 0x7fffu + ((u >> 16) & 1u);
  return (unsigned short)(u >> 16);
}

__device__ __forceinline__ f32x4 mfma16(short8 a, short8 b, f32x4 c) {
  return __builtin_amdgcn_mfma_f32_16x16x32_bf16(a, b, c, 0, 0, 0);
}

#define GLOAD_LDS16(gp, lp)                                                        \
  __builtin_amdgcn_global_load_lds(                                                \
      (const __attribute__((address_space(1))) void*)(gp),                         \
      (__attribute__((address_space(3))) void*)(lp), 16, 0, 0)

// ---------------- converts ----------------

__global__ __launch_bounds__(256) void k_cvt_bf16x8(const float* __restrict__ x,
                                                    short* __restrict__ o) {
  int idx = blockIdx.x * 256 + threadIdx.x;
  const float4* p = (const float4*)x;
  float4 a = p[idx * 2];
  float4 b = p[idx * 2 + 1];
  short8 v;
  v[0] = (short)f2bf(a.x); v[1] = (short)f2bf(a.y);
  v[2] = (short)f2bf(a.z); v[3] = (short)f2bf(a.w);
  v[4] = (short)f2bf(b.x); v[5] = (short)f2bf(b.y);
  v[6] = (short)f2bf(b.z); v[7] = (short)f2bf(b.w);
  *(short8*)&o[idx * 8] = v;
}

__global__ __launch_bounds__(256) void k_cvt_transpose(const float* __restrict__ w,
                                                       short* __restrict__ wt,
                                                       int C) {
  int idx = blockIdx.x * 256 + threadIdx.x;
  int k = idx & 511;
  int n = idx >> 9;
  if (n < C) wt[n * 512 + k] = (short)f2bf(w[k * C + n]);
}

// ---------------- GEMM (128x128 tile, BK=32, 4 waves) ----------------
template <int MODE>
__global__ __launch_bounds__(256) void k_gemm(const short* __restrict__ A,
                                              const short* __restrict__ Bt,
                                              const float* __restrict__ bias,
                                              short* __restrict__ Qo,
                                              short* __restrict__ Ko,
                                              short* __restrict__ VTo,
                                              float* __restrict__ Fo) {
  __shared__ short As[4096];
  __shared__ short Bs[4096];
  const int tid = threadIdx.x;
  const int w = tid >> 6, l = tid & 63, g = l >> 4, c = l & 15;
  const int bm = blockIdx.x * 128, bn = blockIdx.y * 128;
  const int wm = (w >> 1) * 64, wn = (w & 1) * 64;
  const int ch = w * 64 + l;
  const int ar = ch >> 2;
  const int ac = (ch & 3) * 8;
  f32x4 acc[4][4] = {};
  const short* Ap = A + (bm + ar) * 512 + ac;
  const short* Ap2 = Ap + 64 * 512;
  const short* Bp = Bt + (bn + ar) * 512 + ac;
  const short* Bp2 = Bp + 64 * 512;
  short* AsW = &As[w * 512];
  short* BsW = &Bs[w * 512];

  for (int k0 = 0; k0 < 512; k0 += 32) {
    __syncthreads();
    GLOAD_LDS16(Ap + k0, AsW);
    GLOAD_LDS16(Ap2 + k0, AsW + 2048);
    GLOAD_LDS16(Bp + k0, BsW);
    GLOAD_LDS16(Bp2 + k0, BsW + 2048);
    __syncthreads();
    short8 af[4], bfr[4];
#pragma unroll
    for (int mt = 0; mt < 4; mt++)
      af[mt] = *(const short8*)&As[(wm + mt * 16 + c) * 32 + 8 * g];
#pragma unroll
    for (int nt = 0; nt < 4; nt++)
      bfr[nt] = *(const short8*)&Bs[(wn + nt * 16 + c) * 32 + 8 * g];
#pragma unroll
    for (int mt = 0; mt < 4; mt++)
#pragma unroll
      for (int nt = 0; nt < 4; nt++)
        acc[mt][nt] = mfma16(af[mt], bfr[nt], acc[mt][nt]);
  }

  if (MODE == 0) {
#pragma unroll
    for (int nt = 0; nt < 4; nt++) {
      int n = bn + wn + nt * 16 + c;
      float bv = bias[n];
      int h = n / 192;
      int t = n - h * 192;
      int type = t >> 6;
      int hd = t & 63;
#pragma unroll
      for (int mt = 0; mt < 4; mt++) {
        int m0 = bm + wm + mt * 16 + 4 * g;
        int b = m0 >> 11, s0 = m0 & 2047;
        int bh = b * 8 + h;
        if (type == 2) {
          short4v pk;
#pragma unroll
          for (int r = 0; r < 4; r++) pk[r] = (short)f2bf(acc[mt][nt][r] + bv);
          *(short4v*)&VTo[(bh * 64 + hd) * 2048 + s0] = pk;
        } else {
          short* dst = (type == 0) ? Qo : Ko;
#pragma unroll
          for (int r = 0; r < 4; r++)
            dst[(bh * 2048 + s0 + r) * 64 + hd] = (short)f2bf(acc[mt][nt][r] + bv);
        }
      }
    }
  } else {
#pragma unroll
    for (int nt = 0; nt < 4; nt++) {
      int n = bn + wn + nt * 16 + c;
      float bv = bias[n];
#pragma unroll
      for (int mt = 0; mt < 4; mt++) {
        int m0 = bm + wm + mt * 16 + 4 * g;
#pragma unroll
        for (int r = 0; r < 4; r++) Fo[(m0 + r) * 512 + n] = acc[mt][nt][r] + bv;
      }
    }
  }
}

// ---------------- flash attention ----------------
// 512 blocks (LPT order: longest q-chunks dispatched first), 4 waves/block,
// each wave owns 32 q-rows (2 m-frags). V loads issued at iter top; next-K
// prefetched during softmax. No block-level barriers (per-wave P tile).
__global__ __launch_bounds__(256) void k_attn(const short* __restrict__ Q,
                                              const short* __restrict__ K,
                                              const short* __restrict__ VT,
                                              short* __restrict__ ctx) {
  __shared__ short P[4][32][72];
  const int tid = threadIdx.x;
  const int w = tid >> 6, l = tid & 63, g = l >> 4, c = l & 15;
  const int bid = blockIdx.x;
  const int bh = bid & 31;
  const int b = 15 - (bid >> 5);       // descending work: longest first
  const int grp = 4 * b + w;           // q-group 0..63 (32 rows each)
  const int qbase = grp * 32;
  const short* Qb = Q + bh * S_ * HD_;
  const short* Kb = K + bh * S_ * HD_;
  const short* Vb = VT + bh * HD_ * S_;

  short8 qf[2][2];
#pragma unroll
  for (int mf = 0; mf < 2; mf++)
#pragma unroll
    for (int h = 0; h < 2; h++)
      qf[mf][h] = *(const short8*)&Qb[(qbase + mf * 16 + c) * 64 + 8 * g + 32 * h];

  float mi[2][4], li[2][4];
  f32x4 o[2][4];
#pragma unroll
  for (int mf = 0; mf < 2; mf++)
#pragma unroll
    for (int r = 0; r < 4; r++) { mi[mf][r] = -1e30f; li[mf][r] = 0.f; }
#pragma unroll
  for (int mf = 0; mf < 2; mf++)
#pragma unroll
    for (int nt = 0; nt < 4; nt++) o[mf][nt] = f32x4{0.f, 0.f, 0.f, 0.f};

  const float SC = 0.125f * 1.4426950408889634f;
  const int kv_end = qbase + 32;

  short8 kf[4][2];
#pragma unroll
  for (int nt = 0; nt < 4; nt++)
#pragma unroll
    for (int h = 0; h < 2; h++)
      kf[nt][h] = *(const short8*)&Kb[(nt * 16 + c) * 64 + 8 * g + 32 * h];

  for (int kv0 = 0; kv0 < kv_end; kv0 += 64) {
    // V for current tile — issued early, consumed after softmax
    short8 vv[2][4];
#pragma unroll
    for (int kvb = 0; kvb < 2; kvb++)
#pragma unroll
      for (int nt = 0; nt < 4; nt++)
        vv[kvb][nt] = *(const short8*)&Vb[(nt * 16 + c) * S_ + kv0 + kvb * 32 + 8 * g];

    // QK^T on prefetched K
    f32x4 sa[2][4];
#pragma unroll
    for (int mf = 0; mf < 2; mf++)
#pragma unroll
      for (int nt = 0; nt < 4; nt++) {
        sa[mf][nt] = mfma16(qf[mf][0], kf[nt][0], f32x4{0.f, 0.f, 0.f, 0.f});
        sa[mf][nt] = mfma16(qf[mf][1], kf[nt][1], sa[mf][nt]);
      }

    // prefetch next K tile (hides under softmax + PV)
    const bool more = (kv0 + 64) < kv_end;
    if (more) {
#pragma unroll
      for (int nt = 0; nt < 4; nt++)
#pragma unroll
        for (int h = 0; h < 2; h++)
          kf[nt][h] = *(const short8*)&Kb[(kv0 + 64 + nt * 16 + c) * 64 + 8 * g + 32 * h];
    }

    // scale + causal mask (skip mask on fully-valid tiles)
    float sv[2][4][4];
    const bool full = (kv0 + 64) <= qbase;
    if (full) {
#pragma unroll
      for (int mf = 0; mf < 2; mf++)
#pragma unroll
        for (int nt = 0; nt < 4; nt++)
#pragma unroll
          for (int r = 0; r < 4; r++) sv[mf][nt][r] = sa[mf][nt][r] * SC;
    } else {
#pragma unroll
      for (int mf = 0; mf < 2; mf++)
#pragma unroll
        for (int nt = 0; nt < 4; nt++) {
          int kv = kv0 + nt * 16 + c;
#pragma unroll
          for (int r = 0; r < 4; r++) {
            int qrow = qbase + mf * 16 + 4 * g + r;
            sv[mf][nt][r] = (kv <= qrow) ? sa[mf][nt][r] * SC : -1e30f;
          }
        }
    }

    float rmax[2][4];
#pragma unroll
    for (int mf = 0; mf < 2; mf++)
#pragma unroll
      for (int r = 0; r < 4; r++)
        rmax[mf][r] = fmaxf(fmaxf(sv[mf][0][r], sv[mf][1][r]),
                            fmaxf(sv[mf][2][r], sv[mf][3][r]));
#pragma unroll
    for (int off = 1; off < 16; off <<= 1)
#pragma unroll
      for (int mf = 0; mf < 2; mf++)
#pragma unroll
        for (int r = 0; r < 4; r++)
          rmax[mf][r] = fmaxf(rmax[mf][r], __shfl_xor(rmax[mf][r], off, 64));

    float mn[2][4], alpha[2][4], psum[2][4];
    unsigned short pb[2][4][4];
#pragma unroll
    for (int mf = 0; mf < 2; mf++)
#pragma unroll
      for (int r = 0; r < 4; r++) {
        mn[mf][r] = fmaxf(mi[mf][r], rmax[mf][r]);
        alpha[mf][r] = exp2f(mi[mf][r] - mn[mf][r]);
        mi[mf][r] = mn[mf][r];
        psum[mf][r] = 0.f;
      }
#pragma unroll
    for (int mf = 0; mf < 2; mf++)
#pragma unroll
      for (int nt = 0; nt < 4; nt++)
#pragma unroll
        for (int r = 0; r < 4; r++) {
          float p = exp2f(sv[mf][nt][r] - mn[mf][r]);
          psum[mf][r] += p;
          pb[mf][nt][r] = f2bf(p);
        }
#pragma unroll
    for (int off = 1; off < 16; off <<= 1)
#pragma unroll
      for (int mf = 0; mf < 2; mf++)
#pragma unroll
        for (int r = 0; r < 4; r++) psum[mf][r] += __shfl_xor(psum[mf][r], off, 64);
#pragma unroll
    for (int mf = 0; mf < 2; mf++)
#pragma unroll
      for (int r = 0; r < 4; r++) li[mf][r] = li[mf][r] * alpha[mf][r] + psum[mf][r];
#pragma unroll
    for (int mf = 0; mf < 2; mf++)
#pragma unroll
      for (int nt = 0; nt < 4; nt++)
#pragma unroll
        for (int r = 0; r < 4; r++) o[mf][nt][r] *= alpha[mf][r];

    // P -> LDS (per-wave tile) -> A-fragments
#pragma unroll
    for (int mf = 0; mf < 2; mf++)
#pragma unroll
      for (int nt = 0; nt < 4; nt++)
#pragma unroll
        for (int r = 0; r < 4; r++)
          P[w][mf * 16 + 4 * g + r][nt * 16 + c] = (short)pb[mf][nt][r];

#pragma unroll
    for (int kvb = 0; kvb < 2; kvb++) {
      short8 pa0 = *(const short8*)&P[w][c][kvb * 32 + 8 * g];
      short8 pa1 = *(const short8*)&P[w][16 + c][kvb * 32 + 8 * g];
#pragma unroll
      for (int nt = 0; nt < 4; nt++) {
        o[0][nt] = mfma16(pa0, vv[kvb][nt], o[0][nt]);
        o[1][nt] = mfma16(pa1, vv[kvb][nt], o[1][nt]);
      }
    }
  }

  const int bb = bh >> 3, h = bh & 7;
  float inv[2][4];
#pragma unroll
  for (int mf = 0; mf < 2; mf++)
#pragma unroll
    for (int r = 0; r < 4; r++) inv[mf][r] = 1.0f / li[mf][r];
#pragma unroll
  for (int mf = 0; mf < 2; mf++)
#pragma unroll
    for (int nt = 0; nt < 4; nt++)
#pragma unroll
      for (int r = 0; r < 4; r++) {
        int srow = qbase + mf * 16 + 4 * g + r;
        ctx[(bb * S_ + srow) * 512 + h * 64 + nt * 16 + c] =
            (short)f2bf(o[mf][nt][r] * inv[mf][r]);
      }
}

// ---------------- launcher ----------------

extern "C" void kernel_launch(void* const* d_in, const int* in_sizes, int n_in,
                              void* d_out, int out_size, void* d_ws, size_t ws_size,
                              hipStream_t stream) {
  const float* x = (const float*)d_in[0];
  const float* Wqkv = (const float*)d_in[2];
  const float* bqkv = (const float*)d_in[3];
  const float* Wo = (const float*)d_in[4];
  const float* bo = (const float*)d_in[5];
  float* out = (float*)d_out;

  char* ws = (char*)d_ws;
  short* xb    = (short*)(ws + 0);
  short* wqkvt = (short*)(ws + 8388608);
  short* wot   = (short*)(ws + 9961472);
  short* Qw    = (short*)(ws + 10485760);
  short* Kw    = (short*)(ws + 18874368);
  short* VTw   = (short*)(ws + 27262976);
  short* ctx   = (short*)(ws + 35651584);

  k_cvt_bf16x8<<<2048, 256, 0, stream>>>(x, xb);
  k_cvt_transpose<<<3072, 256, 0, stream>>>(Wqkv, wqkvt, 1536);
  k_cvt_transpose<<<1024, 256, 0, stream>>>(Wo, wot, 512);

  dim3 g1(64, 12);
  k_gemm<0><<<g1, 256, 0, stream>>>(xb, wqkvt, bqkv, Qw, Kw, VTw, nullptr);

  k_attn<<<512, 256, 0, stream>>>(Qw, Kw, VTw, ctx);

  dim3 g3(64, 4);
  k_gemm<1><<<g3, 256, 0, stream>>>(ctx, wot, bo, nullptr, nullptr, nullptr, out);
}